// Round 1
// baseline (33430.713 us; speedup 1.0000x reference)
//
#include <hip/hip_runtime.h>
#include <math.h>
#include <stdint.h>

#define T_STEPS 2048
#define XDIM 118
#define EMBD 128
#define HD 1536
#define NA 96
#define NB 128
#define NBLK (NA + NB + 1)

// epoch word layout (uint32 indices into P.ep): separate 64B lines for hot words
#define EP_A   0     // epochA[0..95]
#define EP_B   128   // epochB[0..127]
#define EP_C   256   // epochC (single word)
#define EP_AG  288   // epochAagg (single word, published by B0)
#define EP_N   320

// dynamic LDS: B needs 12288 (xv) + 147456 (weights) + 288 (small) = 160032 B
#define SMEM_BYTES 160032

struct Params {
  const float *x, *h0in, *c0in;
  const float *Wih0, *Whh0, *bih0, *bhh0;
  const float *Wih1, *Whh1, *bih1, *bhh1;
  const float *Whl, *bhl, *Wout, *bout, *Wmap, *bmap;
  float *PRE, *Wc, *bc, *h0buf, *h1buf, *embbuf, *PART;
  uint32_t *ep;
  float *out;
};

__device__ __forceinline__ float bf_lo(uint32_t u){ return __uint_as_float(u << 16); }
__device__ __forceinline__ float bf_hi(uint32_t u){ return __uint_as_float(u & 0xffff0000u); }
__device__ __forceinline__ uint32_t packbf(float a, float b){
  uint32_t ua = __float_as_uint(a), ub = __float_as_uint(b);
  ua = (ua + 0x7fffu + ((ua >> 16) & 1u)) >> 16;           // RNE bf16 (low half)
  ub = (ub + 0x7fffu + ((ub >> 16) & 1u)) & 0xffff0000u;   // RNE bf16 (high half)
  return (ua & 0xffffu) | ub;
}
// Cross-block data via agent-scope relaxed atomics (read/write at the device
// coherence point -> never stale). data->flag ordering: __syncthreads() drains
// vmcnt (stores acked) before the epoch store. No fences, no RMW in the loop.
__device__ __forceinline__ float gload(const float* p){
  return __hip_atomic_load(p, __ATOMIC_RELAXED, __HIP_MEMORY_SCOPE_AGENT);
}
__device__ __forceinline__ void gstore(float* p, float v){
  __hip_atomic_store(p, v, __ATOMIC_RELAXED, __HIP_MEMORY_SCOPE_AGENT);
}
__device__ __forceinline__ uint32_t gloadu(const uint32_t* p){
  return __hip_atomic_load(p, __ATOMIC_RELAXED, __HIP_MEMORY_SCOPE_AGENT);
}
__device__ __forceinline__ void gstoreu(uint32_t* p, uint32_t v){
  __hip_atomic_store(p, v, __ATOMIC_RELAXED, __HIP_MEMORY_SCOPE_AGENT);
}
__device__ __forceinline__ float sigm(float x){ return 1.f / (1.f + __expf(-x)); }

// ---------------- group A: LSTM layer 0 (96 blocks, 16 outputs each) ----------------
// wave w owns all 4 gates of output O=bid*16+w. K=1664 in 13 slots of 128;
// slot p covers k = 128p + 2l, +1 (adjacent pairs -> contiguous b64 LDS reads).
// Regs: p=0..7 (h0) + p=12 (emb). LDS: p=8..11 (h0).
// Waits: phase-1 <- epochAagg>=t (1 word); phase-2 <- epochC>=t (1 word).
__device__ __forceinline__ float asrc(const Params& P, int r, int k){
  if (k < HD) return P.Whh0[(size_t)r * HD + k];
  return P.Wih0[(size_t)r * (XDIM + EMBD) + XDIM + (k - HD)];
}
__device__ void run_A(const Params& P, int bid, uint32_t* smem){
  const int tid = threadIdx.x;
  const int w = tid >> 6, l = tid & 63;
  const int O = bid * 16 + w;
  float* xv = (float*)smem;                 // 1664 floats
  uint2* wl2 = (uint2*)(smem + 1664);       // 2*4*1024 uint2 = 64 KB
  uint32_t wr[4][8];
  uint32_t wremb[4];
#pragma unroll
  for (int g = 0; g < 4; ++g){
    int r = g * HD + O;
#pragma unroll
    for (int p = 0; p < 8; ++p)
      wr[g][p] = packbf(asrc(P, r, 128 * p + 2 * l), asrc(P, r, 128 * p + 2 * l + 1));
#pragma unroll
    for (int q = 0; q < 2; ++q){
      uint2 u;
      u.x = packbf(asrc(P, r, 128 * (8 + 2 * q) + 2 * l), asrc(P, r, 128 * (8 + 2 * q) + 2 * l + 1));
      u.y = packbf(asrc(P, r, 128 * (9 + 2 * q) + 2 * l), asrc(P, r, 128 * (9 + 2 * q) + 2 * l + 1));
      wl2[(q * 4 + g) * 1024 + tid] = u;
    }
    wremb[g] = packbf(asrc(P, r, 1536 + 2 * l), asrc(P, r, 1537 + 2 * l));
  }
  float cst = P.c0in[O];
  int alive = 1;                             // wave-0 lanes only
  __syncthreads();
  for (int t = 0; t < T_STEPS; ++t){
    const float* pre = P.PRE + (size_t)t * 6144;     // prefetch early (plain loads)
    float q0 = pre[O], q1 = pre[HD + O], q2 = pre[2 * HD + O], q3 = pre[3 * HD + O];
    if (w == 0 && alive){                    // all epochA >= t (via B0's aggregate)
      uint32_t n = 0;
      while (gloadu(P.ep + EP_AG) < (uint32_t)t){
        if (++n > 5000000u){ alive = 0; break; }
      }
    }
    __syncthreads();
    const float* hp = P.h0buf + (((t & 1) ^ 1) * HD);
    xv[tid] = gload(hp + tid);
    if (tid < 512) xv[1024 + tid] = gload(hp + 1024 + tid);
    __syncthreads();
    float a0 = 0.f, a1 = 0.f, a2 = 0.f, a3 = 0.f;
#pragma unroll
    for (int p = 0; p < 8; ++p){
      float2 x2 = *(const float2*)&xv[128 * p + 2 * l];
      uint32_t u0 = wr[0][p], u1 = wr[1][p], u2 = wr[2][p], u3 = wr[3][p];
      a0 += bf_lo(u0) * x2.x + bf_hi(u0) * x2.y;
      a1 += bf_lo(u1) * x2.x + bf_hi(u1) * x2.y;
      a2 += bf_lo(u2) * x2.x + bf_hi(u2) * x2.y;
      a3 += bf_lo(u3) * x2.x + bf_hi(u3) * x2.y;
    }
#pragma unroll
    for (int q = 0; q < 2; ++q){
      float2 xa = *(const float2*)&xv[128 * (8 + 2 * q) + 2 * l];
      float2 xb = *(const float2*)&xv[128 * (9 + 2 * q) + 2 * l];
      uint2 u0 = wl2[(q * 4 + 0) * 1024 + tid];
      uint2 u1 = wl2[(q * 4 + 1) * 1024 + tid];
      uint2 u2 = wl2[(q * 4 + 2) * 1024 + tid];
      uint2 u3 = wl2[(q * 4 + 3) * 1024 + tid];
      a0 += bf_lo(u0.x) * xa.x + bf_hi(u0.x) * xa.y + bf_lo(u0.y) * xb.x + bf_hi(u0.y) * xb.y;
      a1 += bf_lo(u1.x) * xa.x + bf_hi(u1.x) * xa.y + bf_lo(u1.y) * xb.x + bf_hi(u1.y) * xb.y;
      a2 += bf_lo(u2.x) * xa.x + bf_hi(u2.x) * xa.y + bf_lo(u2.y) * xb.x + bf_hi(u2.y) * xb.y;
      a3 += bf_lo(u3.x) * xa.x + bf_hi(u3.x) * xa.y + bf_lo(u3.y) * xb.x + bf_hi(u3.y) * xb.y;
    }
    if (w == 0 && alive){                    // emb(t-1) ready
      uint32_t n = 0;
      while (gloadu(P.ep + EP_C) < (uint32_t)t){
        if (++n > 5000000u){ alive = 0; break; }
      }
    }
    __syncthreads();
    if (tid < EMBD) xv[HD + tid] = gload(P.embbuf + (((t & 1) ^ 1) * EMBD) + tid);
    __syncthreads();
    {
      float2 x2 = *(const float2*)&xv[1536 + 2 * l];
      a0 += bf_lo(wremb[0]) * x2.x + bf_hi(wremb[0]) * x2.y;
      a1 += bf_lo(wremb[1]) * x2.x + bf_hi(wremb[1]) * x2.y;
      a2 += bf_lo(wremb[2]) * x2.x + bf_hi(wremb[2]) * x2.y;
      a3 += bf_lo(wremb[3]) * x2.x + bf_hi(wremb[3]) * x2.y;
    }
#pragma unroll
    for (int m = 1; m < 64; m <<= 1){
      a0 += __shfl_xor(a0, m, 64);
      a1 += __shfl_xor(a1, m, 64);
      a2 += __shfl_xor(a2, m, 64);
      a3 += __shfl_xor(a3, m, 64);
    }
    float gi = sigm(a0 + q0);
    float gf = sigm(a1 + q1);
    float gg = tanhf(a2 + q2);
    float go = sigm(a3 + q3);
    cst = gf * cst + gi * gg;
    float hn = go * tanhf(cst);
    if (l == 0) gstore(P.h0buf + (t & 1) * HD + O, hn);
    __syncthreads();                         // drains vmcnt: h0 stores acked
    if (tid == 0) gstoreu(P.ep + EP_A + bid, (uint32_t)(t + 1));
  }
}

// ---------------- group B: LSTM layer 1 (128 blocks, 12 outputs each) ----------------
// 48 gate-rows; wave w owns rows idx=3w+jj (idx=g*12+o). K=3072 in 24 slots;
// slot p: k = 128p+2l,+1.  p=0..11 -> h0(t) [REGS, serial phase-2];
// p=12..23 -> h1(t-1) [LDS, phase-1, overlapped].
// Waits: phase-1 <- epochC>=t (1 word; implies all epochB>=t and PART(t-1)
// consumed); phase-2 <- epochAagg>=t+1 (B0 polls raw epochA and publishes).
__device__ __forceinline__ float bsrc(const Params& P, int r, int k){
  if (k < HD) return P.Wih1[(size_t)r * HD + k];
  return P.Whh1[(size_t)r * HD + (k - HD)];
}
__device__ void run_B(const Params& P, int bidb, uint32_t* smem){
  const int tid = threadIdx.x;
  const int w = tid >> 6, l = tid & 63;
  const int base = bidb * 12;
  float* xv = (float*)smem;                  // 3072 floats = 12288 B
  uint2* wl2 = (uint2*)(smem + 3072);        // 6*3*1024 uint2 = 147456 B
  float* g1lds = (float*)(smem + 39936);     // 48
  float* c1lds = g1lds + 48;                 // 12
  float* h1lds = c1lds + 12;                 // 12
  uint32_t wr[3][12];
  float bias[3];
#pragma unroll
  for (int jj = 0; jj < 3; ++jj){
    int idx = 3 * w + jj;
    int g = idx / 12, o = idx % 12;
    int r = g * HD + base + o;
    bias[jj] = P.bih1[r] + P.bhh1[r];
#pragma unroll
    for (int p = 0; p < 12; ++p)
      wr[jj][p] = packbf(bsrc(P, r, 128 * p + 2 * l), bsrc(P, r, 128 * p + 2 * l + 1));
#pragma unroll
    for (int q = 0; q < 6; ++q){
      uint2 u;
      u.x = packbf(bsrc(P, r, 128 * (12 + 2 * q) + 2 * l), bsrc(P, r, 128 * (12 + 2 * q) + 2 * l + 1));
      u.y = packbf(bsrc(P, r, 128 * (13 + 2 * q) + 2 * l), bsrc(P, r, 128 * (13 + 2 * q) + 2 * l + 1));
      wl2[(q * 3 + jj) * 1024 + tid] = u;
    }
  }
  const int jrow = tid >> 2, cpart = tid & 3;
  float wc0 = 0.f, wc1 = 0.f, wc2 = 0.f;
  if (tid < 512){
    const float* wcp = P.Wc + (size_t)jrow * HD + base + cpart * 3;
    wc0 = wcp[0]; wc1 = wcp[1]; wc2 = wcp[2];
  }
  if (tid < 12) c1lds[tid] = P.c0in[HD + base + tid];
  int alive = 1;
  __syncthreads();
  for (int t = 0; t < T_STEPS; ++t){
    if (w == 0 && alive){                    // epochC>=t: h1(t-1)/PART safety + emb chain
      uint32_t n = 0;
      while (gloadu(P.ep + EP_C) < (uint32_t)t){
        if (++n > 5000000u){ alive = 0; break; }
      }
    }
    __syncthreads();
    const float* h1p = P.h1buf + (((t & 1) ^ 1) * HD);
    xv[1536 + tid] = gload(h1p + tid);
    if (tid < 512) xv[2560 + tid] = gload(h1p + 1024 + tid);
    __syncthreads();
    float a0 = 0.f, a1 = 0.f, a2 = 0.f;
#pragma unroll
    for (int q = 0; q < 6; ++q){             // h1 side (LDS weights) — overlapped phase
      float2 xa = *(const float2*)&xv[128 * (12 + 2 * q) + 2 * l];
      float2 xb = *(const float2*)&xv[128 * (13 + 2 * q) + 2 * l];
      uint2 u0 = wl2[(q * 3 + 0) * 1024 + tid];
      uint2 u1 = wl2[(q * 3 + 1) * 1024 + tid];
      uint2 u2 = wl2[(q * 3 + 2) * 1024 + tid];
      a0 += bf_lo(u0.x) * xa.x + bf_hi(u0.x) * xa.y + bf_lo(u0.y) * xb.x + bf_hi(u0.y) * xb.y;
      a1 += bf_lo(u1.x) * xa.x + bf_hi(u1.x) * xa.y + bf_lo(u1.y) * xb.x + bf_hi(u1.y) * xb.y;
      a2 += bf_lo(u2.x) * xa.x + bf_hi(u2.x) * xa.y + bf_lo(u2.y) * xb.x + bf_hi(u2.y) * xb.y;
    }
    if (w == 0 && alive){                    // h0(t) ready
      uint32_t tgt = (uint32_t)(t + 1), n = 0;
      if (bidb == 0){                        // B0: sole wide poller, publishes aggregate
        while (1){
          uint32_t v0 = gloadu(P.ep + EP_A + l);
          uint32_t v1 = (l < 32) ? gloadu(P.ep + EP_A + 64 + l) : tgt;
          if (__all(v0 >= tgt && v1 >= tgt)) break;
          if (++n > 5000000u){ alive = 0; break; }
        }
        if (l == 0 && alive) gstoreu(P.ep + EP_AG, tgt);
      } else {
        while (gloadu(P.ep + EP_AG) < tgt){
          if (++n > 5000000u){ alive = 0; break; }
        }
      }
    }
    __syncthreads();
    const float* h0p = P.h0buf + (t & 1) * HD;
    xv[tid] = gload(h0p + tid);
    if (tid < 512) xv[1024 + tid] = gload(h0p + 1024 + tid);
    __syncthreads();
#pragma unroll
    for (int p = 0; p < 12; ++p){            // h0 side (reg weights) — serial phase
      float2 x2 = *(const float2*)&xv[128 * p + 2 * l];
      uint32_t u0 = wr[0][p], u1 = wr[1][p], u2 = wr[2][p];
      a0 += bf_lo(u0) * x2.x + bf_hi(u0) * x2.y;
      a1 += bf_lo(u1) * x2.x + bf_hi(u1) * x2.y;
      a2 += bf_lo(u2) * x2.x + bf_hi(u2) * x2.y;
    }
#pragma unroll
    for (int m = 1; m < 64; m <<= 1){
      a0 += __shfl_xor(a0, m, 64);
      a1 += __shfl_xor(a1, m, 64);
      a2 += __shfl_xor(a2, m, 64);
    }
    if (l == 0){
      g1lds[3 * w + 0] = a0 + bias[0];
      g1lds[3 * w + 1] = a1 + bias[1];
      g1lds[3 * w + 2] = a2 + bias[2];
    }
    __syncthreads();
    if (tid < 12){
      int o = tid;
      float gi = sigm(g1lds[o]);
      float gf = sigm(g1lds[12 + o]);
      float gg = tanhf(g1lds[24 + o]);
      float go = sigm(g1lds[36 + o]);
      float c = gf * c1lds[o] + gi * gg;
      c1lds[o] = c;
      float hn = go * tanhf(c);
      h1lds[o] = hn;
      gstore(P.h1buf + (t & 1) * HD + base + o, hn);
    }
    __syncthreads();
    if (tid < 512){
      float pp = wc0 * h1lds[cpart * 3] + wc1 * h1lds[cpart * 3 + 1] + wc2 * h1lds[cpart * 3 + 2];
      pp += __shfl_xor(pp, 1, 64);
      pp += __shfl_xor(pp, 2, 64);
      if (cpart == 0) gstore(P.PART + bidb * 128 + jrow, pp);
    }
    __syncthreads();                         // drains vmcnt: h1 + PART acked
    if (tid == 0) gstoreu(P.ep + EP_B + bidb, (uint32_t)(t + 1));
  }
}

// ---------------- group C: logit-sum + softmax + out + emb (1 block) ----------------
__device__ void run_C(const Params& P, uint32_t* smem){
  const int tid = threadIdx.x;
  float* partred = (float*)smem;             // 1024
  float* lg   = (float*)(smem + 1024);       // 128
  float* plds = (float*)(smem + 1152);       // 128
  float* bcs  = (float*)(smem + 1280);       // 128
  float* red2 = (float*)(smem + 1408);       // 2
  float wm[16];
  const int e = tid >> 3, jc = tid & 7;
#pragma unroll
  for (int i = 0; i < 16; ++i) wm[i] = P.Wmap[(size_t)e * 128 + jc * 16 + i];
  float bm = P.bmap[e];
  if (tid < 128) bcs[tid] = P.bc[tid];
  int alive = 1;
  const int w = tid >> 6, l = tid & 63;
  __syncthreads();
  for (int t = 0; t < T_STEPS; ++t){
    if (w == 0 && alive){                    // sole wide poller of epochB
      uint32_t tgt = (uint32_t)(t + 1), n = 0;
      while (1){
        uint32_t v0 = gloadu(P.ep + EP_B + l);
        uint32_t v1 = gloadu(P.ep + EP_B + 64 + l);
        if (__all(v0 >= tgt && v1 >= tgt)) break;
        if (++n > 5000000u){ alive = 0; break; }
      }
    }
    __syncthreads();
    const int j = tid & 127, b8 = tid >> 7;
    float s = 0.f;
#pragma unroll
    for (int i = 0; i < 16; ++i) s += gload(P.PART + (b8 * 16 + i) * 128 + j);
    partred[b8 * 128 + j] = s;
    __syncthreads();
    if (tid < 128){
      float lt = bcs[tid];
#pragma unroll
      for (int i = 0; i < 8; ++i) lt += partred[i * 128 + tid];
      lg[tid] = lt;
    }
    __syncthreads();
    if (tid < 64){
      float m = fmaxf(lg[tid], lg[tid + 64]);
#pragma unroll
      for (int k = 1; k < 64; k <<= 1) m = fmaxf(m, __shfl_xor(m, k, 64));
      float sd = __expf(lg[tid] - m) + __expf(lg[tid + 64] - m);
#pragma unroll
      for (int k = 1; k < 64; k <<= 1) sd += __shfl_xor(sd, k, 64);
      if (tid == 0){ red2[0] = m; red2[1] = 1.f / sd; }
    }
    __syncthreads();
    if (tid < 128){
      float pv = __expf(lg[tid] - red2[0]) * red2[1];
      plds[tid] = pv;
      P.out[(size_t)t * 128 + tid] = pv;     // host-only consumer: plain store ok
    }
    __syncthreads();
    float a = 0.f;
#pragma unroll
    for (int i = 0; i < 16; ++i) a += wm[i] * plds[jc * 16 + i];
    a += __shfl_xor(a, 1, 64);
    a += __shfl_xor(a, 2, 64);
    a += __shfl_xor(a, 4, 64);
    if (jc == 0) gstore(P.embbuf + (t & 1) * EMBD + e, a + bm);
    __syncthreads();                         // drains vmcnt: emb acked
    if (tid == 0) gstoreu(P.ep + EP_C, (uint32_t)(t + 1));
  }
}

// Per-thread VGPR demand designed to fit the observed 64-reg budget (two attribute
// mechanisms failed to raise it; spills cost ~13 GB/run). Bulk weights live in
// dynamic LDS (160 KB/CU) instead.
__global__ __launch_bounds__(1024) void k_lstm(Params P){
  extern __shared__ __align__(16) uint32_t smem[];
  int bid = blockIdx.x;
  if (bid < NA) run_A(P, bid, smem);
  else if (bid < NA + NB) run_B(P, bid - NA, smem);
  else run_C(P, smem);
}

// ---------------- pre-kernels ----------------
__global__ void k_init(const float* h0in, float* h0buf, float* h1buf, float* embbuf,
                       uint32_t* ep){
  int tid = threadIdx.x;
  for (int i = tid; i < HD; i += 256){
    float a = h0in[i], b = h0in[HD + i];
    h0buf[i] = a; h0buf[HD + i] = a;
    h1buf[i] = b; h1buf[HD + i] = b;
  }
  if (tid < 128){ embbuf[tid] = 0.f; embbuf[128 + tid] = 0.f; }
  for (int i = tid; i < EP_N; i += 256) ep[i] = 0u;
}

// PRE[t][r] = b_ih0[r]+b_hh0[r] + sum_{k<118} W_ih0[r][k]*x[t][k]
__global__ void k_pre(const float* x, const float* Wih0, const float* bih0, const float* bhh0, float* PRE){
  int tb = blockIdx.x >> 2;
  int rc = blockIdx.x & 3;
  int tid = threadIdx.x;
  __shared__ float xl[32 * XDIM];
  for (int i = tid; i < 32 * XDIM; i += 256){
    int tt = i / XDIM, k = i % XDIM;
    xl[i] = x[(size_t)(tb * 32 + tt) * XDIM + k];
  }
  __syncthreads();
  for (int rr = 0; rr < 6; ++rr){
    int r = rc * HD + rr * 256 + tid;
    float acc[32];
#pragma unroll
    for (int t = 0; t < 32; ++t) acc[t] = 0.f;
    const float* wrow = Wih0 + (size_t)r * (XDIM + EMBD);
    for (int k = 0; k < XDIM; ++k){
      float wv = wrow[k];
#pragma unroll
      for (int t = 0; t < 32; ++t) acc[t] += wv * xl[t * XDIM + k];
    }
    float bb = bih0[r] + bhh0[r];
    for (int t = 0; t < 32; ++t)
      PRE[(size_t)(tb * 32 + t) * 6144 + r] = acc[t] + bb;
  }
}

// Wc = W_out @ W_hl (128x1536, K=1024); bc = W_out @ b_hl + b_out
__global__ void k_wc(const float* Whl, const float* Wout, const float* bhl, const float* bout,
                     float* Wc, float* bc){
  if (blockIdx.x == 96){
    int j = threadIdx.x;
    if (j < 128){
      float a = 0.f;
      for (int m = 0; m < 1024; ++m) a += Wout[(size_t)j * 1024 + m] * bhl[m];
      bc[j] = a + bout[j];
    }
    return;
  }
  int kt = blockIdx.x % 6, jt = blockIdx.x / 6;
  __shared__ float wo[8 * 1024];
  int tid = threadIdx.x;
  for (int i = tid; i < 8 * 1024; i += 256) wo[i] = Wout[(size_t)(jt * 8) * 1024 + i];
  __syncthreads();
  int k = kt * 256 + tid;
  float acc[8];
#pragma unroll
  for (int jj = 0; jj < 8; ++jj) acc[jj] = 0.f;
  for (int m = 0; m < 1024; ++m){
    float wl = Whl[(size_t)m * HD + k];
#pragma unroll
    for (int jj = 0; jj < 8; ++jj) acc[jj] += wo[jj * 1024 + m] * wl;
  }
#pragma unroll
  for (int jj = 0; jj < 8; ++jj) Wc[(size_t)(jt * 8 + jj) * HD + k] = acc[jj];
}

__global__ void k_sentinel(float* out){ out[0] = 1.0e6f; }

extern "C" void kernel_launch(void* const* d_in, const int* in_sizes, int n_in,
                              void* d_out, int out_size, void* d_ws, size_t ws_size,
                              hipStream_t stream){
  (void)in_sizes; (void)n_in; (void)out_size;
  const float* x    = (const float*)d_in[0];
  const float* h0in = (const float*)d_in[1];
  const float* c0in = (const float*)d_in[2];
  const float* Wih0 = (const float*)d_in[3];
  const float* Whh0 = (const float*)d_in[4];
  const float* bih0 = (const float*)d_in[5];
  const float* bhh0 = (const float*)d_in[6];
  const float* Wih1 = (const float*)d_in[7];
  const float* Whh1 = (const float*)d_in[8];
  const float* bih1 = (const float*)d_in[9];
  const float* bhh1 = (const float*)d_in[10];
  const float* Whl  = (const float*)d_in[11];
  const float* bhl  = (const float*)d_in[12];
  const float* Wout = (const float*)d_in[13];
  const float* bout = (const float*)d_in[14];
  const float* Wmap = (const float*)d_in[15];
  const float* bmap = (const float*)d_in[16];
  float* out = (float*)d_out;
  float* ws = (float*)d_ws;

  size_t off = 0;
  float* PRE    = ws + off; off += (size_t)T_STEPS * 6144;
  float* Wc     = ws + off; off += 128 * HD;
  float* bc     = ws + off; off += 128;
  float* h0buf  = ws + off; off += 2 * HD;
  float* h1buf  = ws + off; off += 2 * HD;
  float* embbuf = ws + off; off += 2 * EMBD;
  float* PART   = ws + off; off += 128 * 128;
  off = (off + 63) & ~(size_t)63;
  uint32_t* ep  = (uint32_t*)(ws + off); off += EP_N;

  if (ws_size < off * sizeof(float) + 1024){
    hipLaunchKernelGGL(k_sentinel, dim3(1), dim3(1), 0, stream, out);
    return;
  }

  // opt-in to >64KB dynamic LDS (160 KiB/CU on gfx950); unconditional, idempotent
  (void)hipFuncSetAttribute(reinterpret_cast<const void*>(k_lstm),
                            hipFuncAttributeMaxDynamicSharedMemorySize, SMEM_BYTES);

  hipLaunchKernelGGL(k_init, dim3(1), dim3(256), 0, stream, h0in, h0buf, h1buf, embbuf, ep);
  hipLaunchKernelGGL(k_pre, dim3(256), dim3(256), 0, stream, x, Wih0, bih0, bhh0, PRE);
  hipLaunchKernelGGL(k_wc, dim3(97), dim3(256), 0, stream, Whl, Wout, bhl, bout, Wc, bc);

  Params P;
  P.x = x; P.h0in = h0in; P.c0in = c0in;
  P.Wih0 = Wih0; P.Whh0 = Whh0; P.bih0 = bih0; P.bhh0 = bhh0;
  P.Wih1 = Wih1; P.Whh1 = Whh1; P.bih1 = bih1; P.bhh1 = bhh1;
  P.Whl = Whl; P.bhl = bhl; P.Wout = Wout; P.bout = bout; P.Wmap = Wmap; P.bmap = bmap;
  P.PRE = PRE; P.Wc = Wc; P.bc = bc;
  P.h0buf = h0buf; P.h1buf = h1buf; P.embbuf = embbuf; P.PART = PART;
  P.ep = ep; P.out = out;

  hipLaunchKernelGGL(k_lstm, dim3(NBLK), dim3(1024), SMEM_BYTES, stream, P);
}

// Round 2
// 31742.465 us; speedup vs baseline: 1.0532x; 1.0532x over previous
//
#include <hip/hip_runtime.h>
#include <math.h>
#include <stdint.h>

#define T_STEPS 2048
#define XDIM 118
#define EMBD 128
#define HD 1536
#define NA 96
#define NB 128
#define NBLK (NA + NB + 1)

// epoch word layout (uint32 indices into P.ep)
#define EP_A   0     // epochA[0..95]
#define EP_B   128   // epochB[0..127]
#define EP_C   256   // epochC (single word)
#define EP_N   320

// dynamic LDS: B needs 12288 (xv) + 147456 (weights) + 288 (g1/c1) + flags
#define SMEM_BYTES 160048

struct Params {
  const float *x, *h0in, *c0in;
  const float *Wih0, *Whh0, *bih0, *bhh0;
  const float *Wih1, *Whh1, *bih1, *bhh1;
  const float *Whl, *bhl, *Wout, *bout;
  const float *Wfold;
  float *PRE, *Wc, *bc, *h0buf, *h1buf, *ybuf, *PART;
  uint32_t *ep;
  float *out;
};

__device__ __forceinline__ float bf_lo(uint32_t u){ return __uint_as_float(u << 16); }
__device__ __forceinline__ float bf_hi(uint32_t u){ return __uint_as_float(u & 0xffff0000u); }
__device__ __forceinline__ uint32_t packbf(float a, float b){
  uint32_t ua = __float_as_uint(a), ub = __float_as_uint(b);
  ua = (ua + 0x7fffu + ((ua >> 16) & 1u)) >> 16;           // RNE bf16 (low half)
  ub = (ub + 0x7fffu + ((ub >> 16) & 1u)) & 0xffff0000u;   // RNE bf16 (high half)
  return (ua & 0xffffu) | ub;
}
// Cross-block data via agent-scope relaxed atomics (MALL = device coherence point).
__device__ __forceinline__ float gload(const float* p){
  return __hip_atomic_load(p, __ATOMIC_RELAXED, __HIP_MEMORY_SCOPE_AGENT);
}
__device__ __forceinline__ void gstore(float* p, float v){
  __hip_atomic_store(p, v, __ATOMIC_RELAXED, __HIP_MEMORY_SCOPE_AGENT);
}
__device__ __forceinline__ uint32_t gloadu(const uint32_t* p){
  return __hip_atomic_load(p, __ATOMIC_RELAXED, __HIP_MEMORY_SCOPE_AGENT);
}
__device__ __forceinline__ void gstoreu(uint32_t* p, uint32_t v){
  __hip_atomic_store(p, v, __ATOMIC_RELAXED, __HIP_MEMORY_SCOPE_AGENT);
}
__device__ __forceinline__ float sigm(float x){ return 1.f / (1.f + __expf(-x)); }

// LDS mailbox: wave0 observes a global epoch condition, broadcasts via LDS flag.
// Monotonic values -> no reset. Compiler fences pin ordering around the flag.
__device__ __forceinline__ void lds_set(volatile uint32_t* f, uint32_t v){
  asm volatile("" ::: "memory");
  *f = v;
  asm volatile("" ::: "memory");
}
__device__ __forceinline__ void lds_wait(volatile uint32_t* f, uint32_t tgt){
  uint32_t n = 0;
  while (*f < tgt){ if (++n > 1000000000u) break; }
  asm volatile("" ::: "memory");
}

// ---------------- group A: LSTM layer 0 (96 blocks, 16 outputs each) ----------------
// wave w owns all 4 gates of output O=bid*16+w. K slots of 128: p=0..7 h0 (reg
// weights), p=8..11 h0 (LDS weights), final slot = y(t-1) via folded Wfold
// (direct per-wave MALL load, no LDS staging, no barriers).
// Gates: top <- all epochA>=t (wave0 wide-poll + LDS flag); y <- epochC>=t.
__device__ __forceinline__ float asrc(const Params& P, int r, int k){
  if (k < HD) return P.Whh0[(size_t)r * HD + k];
  return P.Wih0[(size_t)r * (XDIM + EMBD) + XDIM + (k - HD)];
}
__device__ void run_A(const Params& P, int bid, uint32_t* smem){
  const int tid = threadIdx.x;
  const int w = tid >> 6, l = tid & 63;
  const int O = bid * 16 + w;
  float* xv = (float*)smem;                 // 1536 floats used
  uint2* wl2 = (uint2*)(smem + 1664);       // 2*4*1024 uint2 = 64 KB
  volatile uint32_t* flg = smem + 18048;    // [0]=flagA, [1]=flagC
  uint32_t wr[4][8];
  uint32_t wry[4];
#pragma unroll
  for (int g = 0; g < 4; ++g){
    int r = g * HD + O;
#pragma unroll
    for (int p = 0; p < 8; ++p)
      wr[g][p] = packbf(asrc(P, r, 128 * p + 2 * l), asrc(P, r, 128 * p + 2 * l + 1));
#pragma unroll
    for (int q = 0; q < 2; ++q){
      uint2 u;
      u.x = packbf(asrc(P, r, 128 * (8 + 2 * q) + 2 * l), asrc(P, r, 128 * (8 + 2 * q) + 2 * l + 1));
      u.y = packbf(asrc(P, r, 128 * (9 + 2 * q) + 2 * l), asrc(P, r, 128 * (9 + 2 * q) + 2 * l + 1));
      wl2[(q * 4 + g) * 1024 + tid] = u;
    }
    wry[g] = packbf(P.Wfold[(size_t)r * 128 + 2 * l], P.Wfold[(size_t)r * 128 + 2 * l + 1]);
  }
  float cst = P.c0in[O];
  int alive = 1;
  if (tid < 2) flg[tid] = 0u;
  __syncthreads();
  for (int t = 0; t < T_STEPS; ++t){
    const float* pre = P.PRE + (size_t)t * 6144;     // prefetch early (plain loads)
    float q0 = pre[O], q1 = pre[HD + O], q2 = pre[2 * HD + O], q3 = pre[3 * HD + O];
    if (w == 0){                             // gate: all epochA >= t
      if (alive && t > 0){
        uint32_t n = 0;
        while (1){
          uint32_t v0 = gloadu(P.ep + EP_A + l);
          uint32_t v1 = (l < 32) ? gloadu(P.ep + EP_A + 64 + l) : (uint32_t)t;
          if (__all(v0 >= (uint32_t)t && v1 >= (uint32_t)t)) break;
          if (++n > 5000000u){ alive = 0; break; }
        }
      }
      if (l == 0) lds_set(flg + 0, (uint32_t)t);
    } else {
      lds_wait(flg + 0, (uint32_t)t);
    }
    const float* hp = P.h0buf + (((t & 1) ^ 1) * HD);
    xv[tid] = gload(hp + tid);
    if (tid < 512) xv[1024 + tid] = gload(hp + 1024 + tid);
    __syncthreads();                         // barrier 1: xv staged
    float a0 = 0.f, a1 = 0.f, a2 = 0.f, a3 = 0.f;
#pragma unroll
    for (int p = 0; p < 8; ++p){
      float2 x2 = *(const float2*)&xv[128 * p + 2 * l];
      uint32_t u0 = wr[0][p], u1 = wr[1][p], u2 = wr[2][p], u3 = wr[3][p];
      a0 += bf_lo(u0) * x2.x + bf_hi(u0) * x2.y;
      a1 += bf_lo(u1) * x2.x + bf_hi(u1) * x2.y;
      a2 += bf_lo(u2) * x2.x + bf_hi(u2) * x2.y;
      a3 += bf_lo(u3) * x2.x + bf_hi(u3) * x2.y;
    }
#pragma unroll
    for (int q = 0; q < 2; ++q){
      float2 xa = *(const float2*)&xv[128 * (8 + 2 * q) + 2 * l];
      float2 xb = *(const float2*)&xv[128 * (9 + 2 * q) + 2 * l];
      uint2 u0 = wl2[(q * 4 + 0) * 1024 + tid];
      uint2 u1 = wl2[(q * 4 + 1) * 1024 + tid];
      uint2 u2 = wl2[(q * 4 + 2) * 1024 + tid];
      uint2 u3 = wl2[(q * 4 + 3) * 1024 + tid];
      a0 += bf_lo(u0.x) * xa.x + bf_hi(u0.x) * xa.y + bf_lo(u0.y) * xb.x + bf_hi(u0.y) * xb.y;
      a1 += bf_lo(u1.x) * xa.x + bf_hi(u1.x) * xa.y + bf_lo(u1.y) * xb.x + bf_hi(u1.y) * xb.y;
      a2 += bf_lo(u2.x) * xa.x + bf_hi(u2.x) * xa.y + bf_lo(u2.y) * xb.x + bf_hi(u2.y) * xb.y;
      a3 += bf_lo(u3.x) * xa.x + bf_hi(u3.x) * xa.y + bf_lo(u3.y) * xb.x + bf_hi(u3.y) * xb.y;
    }
    if (w == 0){                             // gate: y(t-1) ready (epochC >= t)
      if (alive && t > 0){
        uint32_t n = 0;
        while (gloadu(P.ep + EP_C) < (uint32_t)t){
          if (++n > 5000000u){ alive = 0; break; }
        }
      }
      if (l == 0) lds_set(flg + 1, (uint32_t)t);
    } else {
      lds_wait(flg + 1, (uint32_t)t);
    }
    {                                        // y slot: per-wave direct MALL load
      const float* yb = P.ybuf + (((t & 1) ^ 1) * EMBD) + 2 * l;
      float yx = gload(yb), yy = gload(yb + 1);
      a0 += bf_lo(wry[0]) * yx + bf_hi(wry[0]) * yy;
      a1 += bf_lo(wry[1]) * yx + bf_hi(wry[1]) * yy;
      a2 += bf_lo(wry[2]) * yx + bf_hi(wry[2]) * yy;
      a3 += bf_lo(wry[3]) * yx + bf_hi(wry[3]) * yy;
    }
#pragma unroll
    for (int m = 1; m < 64; m <<= 1){
      a0 += __shfl_xor(a0, m, 64);
      a1 += __shfl_xor(a1, m, 64);
      a2 += __shfl_xor(a2, m, 64);
      a3 += __shfl_xor(a3, m, 64);
    }
    float gi = sigm(a0 + q0);
    float gf = sigm(a1 + q1);
    float gg = tanhf(a2 + q2);
    float go = sigm(a3 + q3);
    cst = gf * cst + gi * gg;
    float hn = go * tanhf(cst);
    if (l == 0) gstore(P.h0buf + (t & 1) * HD + O, hn);
    __syncthreads();                         // barrier 2: drains vmcnt + xv protect
    if (tid == 0) gstoreu(P.ep + EP_A + bid, (uint32_t)(t + 1));
  }
}

// ---------------- group B: LSTM layer 1 (128 blocks, 12 outputs each) ----------------
// Gates: top <- epochC>=t (1 word); mid <- all epochA>=t+1 (wave0 wide-poll,
// no aggregator hop). Gate nonlinearity + PART fused into one phase: all 512
// PART threads redundantly compute their 3 h1 values from g1lds; c-state
// double-buffered; tid 0..3 write back c/h1buf.
__device__ __forceinline__ float bsrc(const Params& P, int r, int k){
  if (k < HD) return P.Wih1[(size_t)r * HD + k];
  return P.Whh1[(size_t)r * HD + (k - HD)];
}
__device__ void run_B(const Params& P, int bidb, uint32_t* smem){
  const int tid = threadIdx.x;
  const int w = tid >> 6, l = tid & 63;
  const int base = bidb * 12;
  float* xv = (float*)smem;                  // 3072 floats
  uint2* wl2 = (uint2*)(smem + 3072);        // 147456 B
  float* g1 = (float*)(smem + 39936);        // 48
  float* c1 = g1 + 48;                       // 2*12 double-buffered
  volatile uint32_t* flg = smem + 40008;     // [0]=flagC, [1]=flagA
  uint32_t wr[3][12];
  float bias[3];
#pragma unroll
  for (int jj = 0; jj < 3; ++jj){
    int idx = 3 * w + jj;
    int g = idx / 12, o = idx % 12;
    int r = g * HD + base + o;
    bias[jj] = P.bih1[r] + P.bhh1[r];
#pragma unroll
    for (int p = 0; p < 12; ++p)
      wr[jj][p] = packbf(bsrc(P, r, 128 * p + 2 * l), bsrc(P, r, 128 * p + 2 * l + 1));
#pragma unroll
    for (int q = 0; q < 6; ++q){
      uint2 u;
      u.x = packbf(bsrc(P, r, 128 * (12 + 2 * q) + 2 * l), bsrc(P, r, 128 * (12 + 2 * q) + 2 * l + 1));
      u.y = packbf(bsrc(P, r, 128 * (13 + 2 * q) + 2 * l), bsrc(P, r, 128 * (13 + 2 * q) + 2 * l + 1));
      wl2[(q * 3 + jj) * 1024 + tid] = u;
    }
  }
  const int jrow = tid >> 2, cpart = tid & 3;
  float wc0 = 0.f, wc1 = 0.f, wc2 = 0.f;
  if (tid < 512){
    const float* wcp = P.Wc + (size_t)jrow * HD + base + cpart * 3;
    wc0 = wcp[0]; wc1 = wcp[1]; wc2 = wcp[2];
  }
  if (tid < 12) c1[12 + tid] = P.c0in[HD + base + tid];   // t=0 reads buffer 1
  if (tid < 2) flg[tid] = 0u;
  int alive = 1;
  __syncthreads();
  for (int t = 0; t < T_STEPS; ++t){
    if (w == 0){                             // gate: epochC >= t
      if (alive && t > 0){
        uint32_t n = 0;
        while (gloadu(P.ep + EP_C) < (uint32_t)t){
          if (++n > 5000000u){ alive = 0; break; }
        }
      }
      if (l == 0) lds_set(flg + 0, (uint32_t)t);
    } else {
      lds_wait(flg + 0, (uint32_t)t);
    }
    const float* h1p = P.h1buf + (((t & 1) ^ 1) * HD);
    xv[1536 + tid] = gload(h1p + tid);
    if (tid < 512) xv[2560 + tid] = gload(h1p + 1024 + tid);
    __syncthreads();                         // barrier 1
    float a0 = 0.f, a1 = 0.f, a2 = 0.f;
#pragma unroll
    for (int q = 0; q < 6; ++q){             // h1 side (LDS weights) — overlapped
      float2 xa = *(const float2*)&xv[128 * (12 + 2 * q) + 2 * l];
      float2 xb = *(const float2*)&xv[128 * (13 + 2 * q) + 2 * l];
      uint2 u0 = wl2[(q * 3 + 0) * 1024 + tid];
      uint2 u1 = wl2[(q * 3 + 1) * 1024 + tid];
      uint2 u2 = wl2[(q * 3 + 2) * 1024 + tid];
      a0 += bf_lo(u0.x) * xa.x + bf_hi(u0.x) * xa.y + bf_lo(u0.y) * xb.x + bf_hi(u0.y) * xb.y;
      a1 += bf_lo(u1.x) * xa.x + bf_hi(u1.x) * xa.y + bf_lo(u1.y) * xb.x + bf_hi(u1.y) * xb.y;
      a2 += bf_lo(u2.x) * xa.x + bf_hi(u2.x) * xa.y + bf_lo(u2.y) * xb.x + bf_hi(u2.y) * xb.y;
    }
    if (w == 0){                             // gate: all epochA >= t+1 (direct wide-poll)
      uint32_t tgt = (uint32_t)(t + 1);
      if (alive){
        uint32_t n = 0;
        while (1){
          uint32_t v0 = gloadu(P.ep + EP_A + l);
          uint32_t v1 = (l < 32) ? gloadu(P.ep + EP_A + 64 + l) : tgt;
          if (__all(v0 >= tgt && v1 >= tgt)) break;
          if (++n > 5000000u){ alive = 0; break; }
        }
      }
      if (l == 0) lds_set(flg + 1, tgt);
    } else {
      lds_wait(flg + 1, (uint32_t)(t + 1));
    }
    const float* h0p = P.h0buf + (t & 1) * HD;
    xv[tid] = gload(h0p + tid);
    if (tid < 512) xv[1024 + tid] = gload(h0p + 1024 + tid);
    __syncthreads();                         // barrier 2
#pragma unroll
    for (int p = 0; p < 12; ++p){            // h0 side (reg weights) — serial phase
      float2 x2 = *(const float2*)&xv[128 * p + 2 * l];
      uint32_t u0 = wr[0][p], u1 = wr[1][p], u2 = wr[2][p];
      a0 += bf_lo(u0) * x2.x + bf_hi(u0) * x2.y;
      a1 += bf_lo(u1) * x2.x + bf_hi(u1) * x2.y;
      a2 += bf_lo(u2) * x2.x + bf_hi(u2) * x2.y;
    }
#pragma unroll
    for (int m = 1; m < 64; m <<= 1){
      a0 += __shfl_xor(a0, m, 64);
      a1 += __shfl_xor(a1, m, 64);
      a2 += __shfl_xor(a2, m, 64);
    }
    if (l == 0){
      g1[3 * w + 0] = a0 + bias[0];
      g1[3 * w + 1] = a1 + bias[1];
      g1[3 * w + 2] = a2 + bias[2];
    }
    __syncthreads();                         // barrier 3
    const int par = ((t & 1) ^ 1) * 12, cur = (t & 1) * 12;
    if (tid < 512){                          // fused gate+PART phase
      float h[3], cc[3];
#pragma unroll
      for (int ii = 0; ii < 3; ++ii){
        int o = cpart * 3 + ii;
        float gi = sigm(g1[o]);
        float gf = sigm(g1[12 + o]);
        float gg = tanhf(g1[24 + o]);
        float go = sigm(g1[36 + o]);
        float c = gf * c1[par + o] + gi * gg;
        cc[ii] = c;
        h[ii] = go * tanhf(c);
      }
      float pp = wc0 * h[0] + wc1 * h[1] + wc2 * h[2];
      pp += __shfl_xor(pp, 1, 64);
      pp += __shfl_xor(pp, 2, 64);
      if (cpart == 0) gstore(P.PART + bidb * 128 + jrow, pp);
      if (jrow == 0){                        // tid 0..3: writer for outputs cpart*3..+2
#pragma unroll
        for (int ii = 0; ii < 3; ++ii){
          int o = cpart * 3 + ii;
          c1[cur + o] = cc[ii];
          gstore(P.h1buf + (t & 1) * HD + base + o, h[ii]);
        }
      }
    }
    __syncthreads();                         // barrier 4: drains vmcnt (h1 + PART)
    if (tid == 0) gstoreu(P.ep + EP_B + bidb, (uint32_t)(t + 1));
  }
}

// ---------------- group C: logit-sum + softmax + y (1 block, 1 barrier/step) ----------------
__device__ void run_C(const Params& P, uint32_t* smem){
  const int tid = threadIdx.x;
  float* partred = (float*)smem;             // 1024
  float* bcs = (float*)(smem + 1024);        // 128
  volatile uint32_t* flg = smem + 1152;      // flagB
  const int w = tid >> 6, l = tid & 63;
  if (tid < 128) bcs[tid] = P.bc[tid];
  if (tid == 0) flg[0] = 0u;
  int alive = 1;
  __syncthreads();
  for (int t = 0; t < T_STEPS; ++t){
    uint32_t tgt = (uint32_t)(t + 1);
    if (w == 0){                             // gate: all epochB >= t+1 (wide-poll)
      if (alive){
        uint32_t n = 0;
        while (1){
          uint32_t v0 = gloadu(P.ep + EP_B + l);
          uint32_t v1 = gloadu(P.ep + EP_B + 64 + l);
          if (__all(v0 >= tgt && v1 >= tgt)) break;
          if (++n > 5000000u){ alive = 0; break; }
        }
      }
      if (l == 0) lds_set(flg, tgt);
    } else {
      lds_wait(flg, tgt);
    }
    const int j = tid & 127, b8 = tid >> 7;  // all 1024 threads gather PART
    float s = 0.f;
#pragma unroll
    for (int i = 0; i < 16; ++i) s += gload(P.PART + (b8 * 16 + i) * 128 + j);
    partred[b8 * 128 + j] = s;
    __syncthreads();                         // the only barrier
    if (w == 0){                             // wave0 finishes the step alone
      float lt0 = bcs[l], lt1 = bcs[64 + l];
#pragma unroll
      for (int i = 0; i < 8; ++i){
        lt0 += partred[i * 128 + l];
        lt1 += partred[i * 128 + 64 + l];
      }
      float m = fmaxf(lt0, lt1);
#pragma unroll
      for (int k = 1; k < 64; k <<= 1) m = fmaxf(m, __shfl_xor(m, k, 64));
      float e0 = __expf(lt0 - m), e1 = __expf(lt1 - m);
      float sd = e0 + e1;
#pragma unroll
      for (int k = 1; k < 64; k <<= 1) sd += __shfl_xor(sd, k, 64);
      float inv = 1.f / sd;
      float p0 = e0 * inv, p1 = e1 * inv;
      P.out[(size_t)t * 128 + l] = p0;       // host-only consumer: plain store ok
      P.out[(size_t)t * 128 + 64 + l] = p1;
      gstore(P.ybuf + (t & 1) * EMBD + l, p0);
      gstore(P.ybuf + (t & 1) * EMBD + 64 + l, p1);
      if (l == 0)                            // release drains the wave's stores
        __hip_atomic_store(P.ep + EP_C, tgt, __ATOMIC_RELEASE, __HIP_MEMORY_SCOPE_AGENT);
    }
    // next-iter partred overwrite is safe: flagB(t+2) requires EP_B(t+2) which
    // requires EP_C(t+1), published only after wave0's partred reads above.
  }
}

__global__ __launch_bounds__(1024) void k_lstm(Params P){
  extern __shared__ __align__(16) uint32_t smem[];
  int bid = blockIdx.x;
  if (bid < NA) run_A(P, bid, smem);
  else if (bid < NA + NB) run_B(P, bid - NA, smem);
  else run_C(P, smem);
}

// ---------------- pre-kernels ----------------
__global__ void k_init(const float* h0in, float* h0buf, float* h1buf, float* ybuf,
                       uint32_t* ep){
  int tid = threadIdx.x;
  for (int i = tid; i < HD; i += 256){
    float a = h0in[i], b = h0in[HD + i];
    h0buf[i] = a; h0buf[HD + i] = a;
    h1buf[i] = b; h1buf[HD + i] = b;
  }
  if (tid < 128){ ybuf[tid] = 0.f; ybuf[128 + tid] = 0.f; }
  for (int i = tid; i < EP_N; i += 256) ep[i] = 0u;
}

// Wfold[r][j] = sum_e Wih0[r][118+e] * Wmap[e][j]; bfold[r] = sum_e Wih0[r][118+e]*bmap[e]
__global__ void k_fold(const float* Wih0, const float* Wmap, const float* bmap,
                       float* Wfold, float* bfold){
  __shared__ float we[64 * 128];
  int b = blockIdx.x, tid = threadIdx.x;
  int r0 = b * 64;
  for (int i = tid; i < 64 * 128; i += 256){
    int rr = i >> 7, e = i & 127;
    we[i] = Wih0[(size_t)(r0 + rr) * (XDIM + EMBD) + XDIM + e];
  }
  __syncthreads();
  int j = tid & 127, half = tid >> 7;
  float acc[32];
#pragma unroll
  for (int rr = 0; rr < 32; ++rr) acc[rr] = 0.f;
  for (int e = 0; e < 128; ++e){
    float wv = Wmap[(size_t)e * 128 + j];
#pragma unroll
    for (int rr = 0; rr < 32; ++rr) acc[rr] += we[(half * 32 + rr) * 128 + e] * wv;
  }
  for (int rr = 0; rr < 32; ++rr)
    Wfold[(size_t)(r0 + half * 32 + rr) * 128 + j] = acc[rr];
  if (tid < 64){
    float a = 0.f;
    for (int e = 0; e < 128; ++e) a += we[tid * 128 + e] * bmap[e];
    bfold[r0 + tid] = a;
  }
}

// PRE[t][r] = b_ih0[r]+b_hh0[r] + (t>0 ? bfold[r] : 0) + sum_{k<118} W_ih0[r][k]*x[t][k]
__global__ void k_pre(const float* x, const float* Wih0, const float* bih0, const float* bhh0,
                      const float* bfold, float* PRE){
  int tb = blockIdx.x >> 2;
  int rc = blockIdx.x & 3;
  int tid = threadIdx.x;
  __shared__ float xl[32 * XDIM];
  for (int i = tid; i < 32 * XDIM; i += 256){
    int tt = i / XDIM, k = i % XDIM;
    xl[i] = x[(size_t)(tb * 32 + tt) * XDIM + k];
  }
  __syncthreads();
  for (int rr = 0; rr < 6; ++rr){
    int r = rc * HD + rr * 256 + tid;
    float acc[32];
#pragma unroll
    for (int t = 0; t < 32; ++t) acc[t] = 0.f;
    const float* wrow = Wih0 + (size_t)r * (XDIM + EMBD);
    for (int k = 0; k < XDIM; ++k){
      float wv = wrow[k];
#pragma unroll
      for (int t = 0; t < 32; ++t) acc[t] += wv * xl[t * XDIM + k];
    }
    float bb = bih0[r] + bhh0[r];
    float bf = bfold[r];
    for (int t = 0; t < 32; ++t)
      PRE[(size_t)(tb * 32 + t) * 6144 + r] = acc[t] + bb + ((tb * 32 + t) > 0 ? bf : 0.f);
  }
}

// Wc = W_out @ W_hl (128x1536, K=1024); bc = W_out @ b_hl + b_out
__global__ void k_wc(const float* Whl, const float* Wout, const float* bhl, const float* bout,
                     float* Wc, float* bc){
  if (blockIdx.x == 96){
    int j = threadIdx.x;
    if (j < 128){
      float a = 0.f;
      for (int m = 0; m < 1024; ++m) a += Wout[(size_t)j * 1024 + m] * bhl[m];
      bc[j] = a + bout[j];
    }
    return;
  }
  int kt = blockIdx.x % 6, jt = blockIdx.x / 6;
  __shared__ float wo[8 * 1024];
  int tid = threadIdx.x;
  for (int i = tid; i < 8 * 1024; i += 256) wo[i] = Wout[(size_t)(jt * 8) * 1024 + i];
  __syncthreads();
  int k = kt * 256 + tid;
  float acc[8];
#pragma unroll
  for (int jj = 0; jj < 8; ++jj) acc[jj] = 0.f;
  for (int m = 0; m < 1024; ++m){
    float wl = Whl[(size_t)m * HD + k];
#pragma unroll
    for (int jj = 0; jj < 8; ++jj) acc[jj] += wo[jj * 1024 + m] * wl;
  }
#pragma unroll
  for (int jj = 0; jj < 8; ++jj) Wc[(size_t)(jt * 8 + jj) * HD + k] = acc[jj];
}

__global__ void k_sentinel(float* out){ out[0] = 1.0e6f; }

extern "C" void kernel_launch(void* const* d_in, const int* in_sizes, int n_in,
                              void* d_out, int out_size, void* d_ws, size_t ws_size,
                              hipStream_t stream){
  (void)in_sizes; (void)n_in; (void)out_size;
  const float* x    = (const float*)d_in[0];
  const float* h0in = (const float*)d_in[1];
  const float* c0in = (const float*)d_in[2];
  const float* Wih0 = (const float*)d_in[3];
  const float* Whh0 = (const float*)d_in[4];
  const float* bih0 = (const float*)d_in[5];
  const float* bhh0 = (const float*)d_in[6];
  const float* Wih1 = (const float*)d_in[7];
  const float* Whh1 = (const float*)d_in[8];
  const float* bih1 = (const float*)d_in[9];
  const float* bhh1 = (const float*)d_in[10];
  const float* Whl  = (const float*)d_in[11];
  const float* bhl  = (const float*)d_in[12];
  const float* Wout = (const float*)d_in[13];
  const float* bout = (const float*)d_in[14];
  const float* Wmap = (const float*)d_in[15];
  const float* bmap = (const float*)d_in[16];
  float* out = (float*)d_out;
  float* ws = (float*)d_ws;

  size_t off = 0;
  float* PRE    = ws + off; off += (size_t)T_STEPS * 6144;
  float* Wc     = ws + off; off += 128 * HD;
  float* bc     = ws + off; off += 128;
  float* Wfold  = ws + off; off += (size_t)6144 * 128;
  float* bfold  = ws + off; off += 6144;
  float* h0buf  = ws + off; off += 2 * HD;
  float* h1buf  = ws + off; off += 2 * HD;
  float* ybuf   = ws + off; off += 2 * EMBD;
  float* PART   = ws + off; off += 128 * 128;
  off = (off + 63) & ~(size_t)63;
  uint32_t* ep  = (uint32_t*)(ws + off); off += EP_N;

  if (ws_size < off * sizeof(float) + 1024){
    hipLaunchKernelGGL(k_sentinel, dim3(1), dim3(1), 0, stream, out);
    return;
  }

  // opt-in to >64KB dynamic LDS (160 KiB/CU on gfx950); unconditional, idempotent
  (void)hipFuncSetAttribute(reinterpret_cast<const void*>(k_lstm),
                            hipFuncAttributeMaxDynamicSharedMemorySize, SMEM_BYTES);

  hipLaunchKernelGGL(k_init, dim3(1), dim3(256), 0, stream, h0in, h0buf, h1buf, ybuf, ep);
  hipLaunchKernelGGL(k_fold, dim3(96), dim3(256), 0, stream, Wih0, Wmap, bmap, Wfold, bfold);
  hipLaunchKernelGGL(k_pre, dim3(256), dim3(256), 0, stream, x, Wih0, bih0, bhh0, bfold, PRE);
  hipLaunchKernelGGL(k_wc, dim3(97), dim3(256), 0, stream, Whl, Wout, bhl, bout, Wc, bc);

  Params P;
  P.x = x; P.h0in = h0in; P.c0in = c0in;
  P.Wih0 = Wih0; P.Whh0 = Whh0; P.bih0 = bih0; P.bhh0 = bhh0;
  P.Wih1 = Wih1; P.Whh1 = Whh1; P.bih1 = bih1; P.bhh1 = bhh1;
  P.Whl = Whl; P.bhl = bhl; P.Wout = Wout; P.bout = bout;
  P.Wfold = Wfold;
  P.PRE = PRE; P.Wc = Wc; P.bc = bc;
  P.h0buf = h0buf; P.h1buf = h1buf; P.ybuf = ybuf; P.PART = PART;
  P.ep = ep; P.out = out;

  hipLaunchKernelGGL(k_lstm, dim3(NBLK), dim3(1024), SMEM_BYTES, stream, P);
}